// Round 1
// baseline (311.384 us; speedup 1.0000x reference)
//
#include <hip/hip_runtime.h>
#include <stdint.h>

#define NTOK   16384      // B*T = 4*4096
#define DM     1024
#define DI     512
#define NH     8
#define DH     64
#define CHUNK  64
#define NCH    64         // T / CHUNK
#define NBHC   2048       // B*H*NCH

using short8 = __attribute__((ext_vector_type(8))) short;
using f32x4  = __attribute__((ext_vector_type(4))) float;

__device__ __forceinline__ unsigned short f2bf(float f) {
  union { float f; unsigned int u; } x; x.f = f;
  unsigned int u = x.u;
  return (unsigned short)((u + 0x7fffu + ((u >> 16) & 1u)) >> 16);
}
__device__ __forceinline__ float bf2f(unsigned short h) {
  union { unsigned int u; float f; } x; x.u = ((unsigned int)h) << 16; return x.f;
}

typedef const __attribute__((address_space(1))) void* gp1_t;
typedef __attribute__((address_space(3))) void* lp3_t;
__device__ __forceinline__ void gload_lds16(const void* g, void* l) {
  __builtin_amdgcn_global_load_lds((gp1_t)g, (lp3_t)l, 16, 0, 0);
}

// ---------------- K0: fused init: LN (blocks 0..16383), W transposes ---------
__global__ __launch_bounds__(256) void init_kernel(const float* __restrict__ x,
                                                   const float* __restrict__ gamma,
                                                   const float* __restrict__ beta,
                                                   const float* __restrict__ Wq,
                                                   const float* __restrict__ Wk,
                                                   const float* __restrict__ Wv,
                                                   const float* __restrict__ Wa,
                                                   const float* __restrict__ Wo,
                                                   unsigned short* __restrict__ xn,
                                                   unsigned short* __restrict__ Wt,
                                                   unsigned short* __restrict__ Wot) {
  const int blk = blockIdx.x, tid = threadIdx.x;
  __shared__ float tile[32][33];
  __shared__ float rs_[4], rss_[4];
  if (blk < NTOK) {
    const int row = blk;
    float4 v = ((const float4*)(x + (long)row * DM))[tid];
    float s  = v.x + v.y + v.z + v.w;
    float ss = v.x * v.x + v.y * v.y + v.z * v.z + v.w * v.w;
    #pragma unroll
    for (int off = 32; off > 0; off >>= 1) { s += __shfl_down(s, off); ss += __shfl_down(ss, off); }
    int wave = tid >> 6, lane = tid & 63;
    if (lane == 0) { rs_[wave] = s; rss_[wave] = ss; }
    __syncthreads();
    s  = rs_[0] + rs_[1] + rs_[2] + rs_[3];
    ss = rss_[0] + rss_[1] + rss_[2] + rss_[3];
    float mu   = s * (1.f / DM);
    float var  = ss * (1.f / DM) - mu * mu;
    float rstd = rsqrtf(var + 1e-5f);
    int idx = tid * 4;
    float xv[4] = {v.x, v.y, v.z, v.w};
    unsigned short o[4];
    #pragma unroll
    for (int j = 0; j < 4; ++j) o[j] = f2bf((xv[j] - mu) * rstd * gamma[idx + j] + beta[idx + j]);
    uint2 pk; pk.x = (unsigned)o[0] | ((unsigned)o[1] << 16); pk.y = (unsigned)o[2] | ((unsigned)o[3] << 16);
    *(uint2*)(xn + (long)row * DM + idx) = pk;
  } else if (blk < NTOK + 2048) {
    const int id = blk - NTOK;
    const int z = id >> 9, r9 = id & 511;
    const float* in = (z == 0) ? Wq : (z == 1) ? Wk : (z == 2) ? Wv : Wa;
    unsigned short* o = Wt + (size_t)z * 512 * 1024;
    int bx = (r9 & 15) * 32, by = (r9 >> 4) * 32;
    int tx = tid & 31, ty = tid >> 5;
    #pragma unroll
    for (int r = ty; r < 32; r += 8) tile[r][tx] = in[(long)(by + r) * 512 + bx + tx];
    __syncthreads();
    #pragma unroll
    for (int r = ty; r < 32; r += 8) o[(long)(bx + r) * 1024 + by + tx] = f2bf(tile[tx][r]);
  } else {
    const int id = blk - NTOK - 2048;
    int bx = (id & 31) * 32, by = (id >> 5) * 32;
    int tx = tid & 31, ty = tid >> 5;
    #pragma unroll
    for (int r = ty; r < 32; r += 8) tile[r][tx] = Wo[(long)(by + r) * 1024 + bx + tx];
    __syncthreads();
    #pragma unroll
    for (int r = ty; r < 32; r += 8) Wot[(long)(bx + r) * 512 + by + tx] = f2bf(tile[tx][r]);
  }
}

// ---------------- GEMM: C[M][N] = A(bf16 MxK) * Bt(bf16 NxK)^T ---------------
// 256x256 tile, BK=64, 512 threads = 8 waves (2M x 4N), per-wave 128x64 out.
// 8-phase-style schedule: per K-tile 4 quadrant phases, raw s_barrier (NO
// vmcnt drain inside tile), all 8 next-tile gload_lds issued in phases 1-2,
// single vmcnt(0) at tile boundary (~3 phases after issue -> nearly free).
// LDS: 2 x (A 256x64 + B 256x64) bf16 = 128 KiB, double-buffered.
// T2 swizzle: logical byte col c at row r stored at c ^ ((r&7)<<4); applied
// via pre-swizzled GLOBAL source (gload_lds dest stays linear) + swizzled
// ds_read address. row&7 == l16&7 for every fragment -> uniform bank spread.
#define EPSW 264   // epilogue LDS row stride (ushorts), 256+8
template <int MODE>
__global__ __launch_bounds__(512, 2) void gemm8(const unsigned short* __restrict__ A,
                                                const unsigned short* __restrict__ Bt,
                                                unsigned short* __restrict__ Cb,
                                                float* __restrict__ Cf,
                                                const float* __restrict__ resid,
                                                int M, int N, int K) {
  __shared__ __align__(16) unsigned short sm[65536];   // 128 KiB
  const int tid = threadIdx.x;
  const int wave = tid >> 6, lane = tid & 63;
  const int quad = lane >> 4, l16 = lane & 15;
  const int wm = wave >> 2, wn = wave & 3;

  // T1: bijective XCD swizzle; chunk is n-major so each XCD reuses one B panel
  const int nwg = gridDim.x;
  const int cpx = nwg >> 3;
  const int bid = blockIdx.x;
  const int swz = (bid & 7) * cpx + (bid >> 3);
  const int m0 = (swz & 63) * 256;
  const int n0 = (swz >> 6) * 256;

  // staging constants: thread stages 16B at linear LDS byte p = u*8192 + tid*16
  // row = u*64 + (tid>>3); logical col byte = ((tid&7)*16) ^ ((row&7)<<4)
  const int rloc = tid >> 3;
  const int cbu = ((((tid & 7) << 4) ^ ((rloc & 7) << 4)) >> 1);  // ushort units
  const unsigned short* ap = A + (long)(m0 + rloc) * K + cbu;
  const unsigned short* bp = Bt + (long)(n0 + rloc) * K + cbu;
  const int dst = tid * 8;   // ushort index within region

  // fragment-read constants (ushort offsets); swizzle uses l16&7 == row&7
  const int colu0 = (((quad << 4) ^ ((l16 & 7) << 4)) >> 1);
  const int colu1 = colu0 ^ 32;
  const int aoff = (wm * 128 + l16) * 64;          // A region base row offset
  const int boff = 16384 + (wn * 64 + l16) * 64;   // B region

  f32x4 acc[8][4];
  #pragma unroll
  for (int i = 0; i < 8; ++i)
    #pragma unroll
    for (int j = 0; j < 4; ++j) acc[i][j] = (f32x4){0.f, 0.f, 0.f, 0.f};

  const int NT = K >> 6;

  // prologue: stage K-tile 0 into buf 0
  #pragma unroll
  for (int u = 0; u < 4; ++u) {
    gload_lds16(ap + (long)u * 64 * K, &sm[u * 4096 + dst]);
    gload_lds16(bp + (long)u * 64 * K, &sm[16384 + u * 4096 + dst]);
  }
  asm volatile("s_waitcnt vmcnt(0)" ::: "memory");
  __builtin_amdgcn_s_barrier();
  __builtin_amdgcn_sched_barrier(0);

  short8 aR[4][2];        // current mh's A frags [mt][ksub]
  short8 bR[2][2][2];     // both nh's B frags   [nh][nt][ksub]

  for (int t = 0; t < NT; ++t) {
    const unsigned short* sc = sm + (t & 1) * 32768;
    unsigned short* sn = sm + ((t + 1) & 1) * 32768;
    const unsigned short* apn = ap + (long)(t + 1) * 64;
    const unsigned short* bpn = bp + (long)(t + 1) * 64;
    const bool more = (t + 1 < NT);

    // ---------- phase 1: quadrant (mh=0, nh=0); stage next A rounds 0-3 ------
    #pragma unroll
    for (int mt = 0; mt < 4; ++mt) {
      aR[mt][0] = *(const short8*)&sc[aoff + mt * 1024 + colu0];
      aR[mt][1] = *(const short8*)&sc[aoff + mt * 1024 + colu1];
    }
    #pragma unroll
    for (int nt = 0; nt < 2; ++nt) {
      bR[0][nt][0] = *(const short8*)&sc[boff + nt * 1024 + colu0];
      bR[0][nt][1] = *(const short8*)&sc[boff + nt * 1024 + colu1];
    }
    if (more) {
      gload_lds16(apn,                  &sn[dst]);
      gload_lds16(apn + (long) 64 * K,  &sn[4096 + dst]);
      gload_lds16(apn + (long)128 * K,  &sn[8192 + dst]);
      gload_lds16(apn + (long)192 * K,  &sn[12288 + dst]);
    }
    __builtin_amdgcn_s_barrier();
    __builtin_amdgcn_s_setprio(1);
    #pragma unroll
    for (int mt = 0; mt < 4; ++mt)
      #pragma unroll
      for (int nt = 0; nt < 2; ++nt) {
        acc[mt][nt] = __builtin_amdgcn_mfma_f32_16x16x32_bf16(aR[mt][0], bR[0][nt][0], acc[mt][nt], 0, 0, 0);
        acc[mt][nt] = __builtin_amdgcn_mfma_f32_16x16x32_bf16(aR[mt][1], bR[0][nt][1], acc[mt][nt], 0, 0, 0);
      }
    __builtin_amdgcn_s_setprio(0);
    __builtin_amdgcn_s_barrier();

    // ---------- phase 2: quadrant (0,1); stage next B rounds 0-3 -------------
    #pragma unroll
    for (int nt = 0; nt < 2; ++nt) {
      bR[1][nt][0] = *(const short8*)&sc[boff + (nt + 2) * 1024 + colu0];
      bR[1][nt][1] = *(const short8*)&sc[boff + (nt + 2) * 1024 + colu1];
    }
    if (more) {
      gload_lds16(bpn,                  &sn[16384 + dst]);
      gload_lds16(bpn + (long) 64 * K,  &sn[16384 + 4096 + dst]);
      gload_lds16(bpn + (long)128 * K,  &sn[16384 + 8192 + dst]);
      gload_lds16(bpn + (long)192 * K,  &sn[16384 + 12288 + dst]);
    }
    __builtin_amdgcn_s_barrier();
    __builtin_amdgcn_s_setprio(1);
    #pragma unroll
    for (int mt = 0; mt < 4; ++mt)
      #pragma unroll
      for (int nt = 0; nt < 2; ++nt) {
        acc[mt][nt + 2] = __builtin_amdgcn_mfma_f32_16x16x32_bf16(aR[mt][0], bR[1][nt][0], acc[mt][nt + 2], 0, 0, 0);
        acc[mt][nt + 2] = __builtin_amdgcn_mfma_f32_16x16x32_bf16(aR[mt][1], bR[1][nt][1], acc[mt][nt + 2], 0, 0, 0);
      }
    __builtin_amdgcn_s_setprio(0);
    __builtin_amdgcn_s_barrier();

    // ---------- phase 3: quadrant (1,1) --------------------------------------
    #pragma unroll
    for (int mt = 0; mt < 4; ++mt) {
      aR[mt][0] = *(const short8*)&sc[aoff + 4096 + mt * 1024 + colu0];
      aR[mt][1] = *(const short8*)&sc[aoff + 4096 + mt * 1024 + colu1];
    }
    __builtin_amdgcn_s_barrier();
    __builtin_amdgcn_s_setprio(1);
    #pragma unroll
    for (int mt = 0; mt < 4; ++mt)
      #pragma unroll
      for (int nt = 0; nt < 2; ++nt) {
        acc[4 + mt][nt + 2] = __builtin_amdgcn_mfma_f32_16x16x32_bf16(aR[mt][0], bR[1][nt][0], acc[4 + mt][nt + 2], 0, 0, 0);
        acc[4 + mt][nt + 2] = __builtin_amdgcn_mfma_f32_16x16x32_bf16(aR[mt][1], bR[1][nt][1], acc[4 + mt][nt + 2], 0, 0, 0);
      }
    __builtin_amdgcn_s_setprio(0);
    __builtin_amdgcn_s_barrier();

    // ---------- phase 4: quadrant (1,0); tile-boundary drain -----------------
    __builtin_amdgcn_s_barrier();
    __builtin_amdgcn_s_setprio(1);
    #pragma unroll
    for (int mt = 0; mt < 4; ++mt)
      #pragma unroll
      for (int nt = 0; nt < 2; ++nt) {
        acc[4 + mt][nt] = __builtin_amdgcn_mfma_f32_16x16x32_bf16(aR[mt][0], bR[0][nt][0], acc[4 + mt][nt], 0, 0, 0);
        acc[4 + mt][nt] = __builtin_amdgcn_mfma_f32_16x16x32_bf16(aR[mt][1], bR[0][nt][1], acc[4 + mt][nt], 0, 0, 0);
      }
    __builtin_amdgcn_s_setprio(0);
    if (more) asm volatile("s_waitcnt vmcnt(0)" ::: "memory");
    __builtin_amdgcn_s_barrier();        // boundary: buf[cur] free, buf[next] ready
    __builtin_amdgcn_sched_barrier(0);
  }

  // ---------------- epilogue via LDS (two 128-row passes) --------------------
  unsigned short* epi = sm;
  #pragma unroll
  for (int h = 0; h < 2; ++h) {
    if (wm == h) {
      #pragma unroll
      for (int fm = 0; fm < 8; ++fm)
        #pragma unroll
        for (int fn = 0; fn < 4; ++fn)
          #pragma unroll
          for (int r = 0; r < 4; ++r)
            epi[(fm * 16 + quad * 4 + r) * EPSW + wn * 64 + fn * 16 + l16] = f2bf(acc[fm][fn][r]);
    }
    __syncthreads();
    if (MODE == 0) {
      #pragma unroll
      for (int i = tid; i < 4096; i += 512) {
        int row = i >> 5, cc = (i & 31) * 8;
        uint4 v = *(const uint4*)&epi[row * EPSW + cc];
        *(uint4*)&Cb[(long)(m0 + h * 128 + row) * N + n0 + cc] = v;
      }
    } else {
      #pragma unroll
      for (int i = tid; i < 8192; i += 512) {
        int row = i >> 6, cc = (i & 63) * 4;
        long g = (long)(m0 + h * 128 + row) * N + n0 + cc;
        float4 rv = *(const float4*)&resid[g];
        uint2 pv = *(const uint2*)&epi[row * EPSW + cc];
        float4 ov;
        ov.x = bf2f((unsigned short)(pv.x & 0xffffu)) + rv.x;
        ov.y = bf2f((unsigned short)(pv.x >> 16))     + rv.y;
        ov.z = bf2f((unsigned short)(pv.y & 0xffffu)) + rv.z;
        ov.w = bf2f((unsigned short)(pv.y >> 16))     + rv.w;
        *(float4*)&Cf[g] = ov;
      }
    }
    __syncthreads();
  }
}

// ---------------- K3: fused per-chunk prep + intra-chunk attention -----------
#define TS 72
__global__ __launch_bounds__(256) void prep_intra_kernel(const unsigned short* __restrict__ Cb,
                                                         const float* __restrict__ ba,
                                                         unsigned short* __restrict__ qt,
                                                         float* __restrict__ Dvec,
                                                         unsigned short* __restrict__ Ointra,
                                                         unsigned short* __restrict__ Tt) {
  const int bhc = blockIdx.x;
  const int c = bhc & 63, bh = bhc >> 6;
  const int h = bh & 7, b = bh >> 3;
  const int tid = threadIdx.x;
  __shared__ __align__(16) unsigned short Qb[4096], Kb[4096], Vb[4096], lamB[4096];
  __shared__ __align__(16) unsigned short Vt[64 * TS], Kt[64 * TS];
  __shared__ float rnF[64], lendF[64];
  const long rowbase = ((long)(b * 4096 + c * 64)) * 2048;
  const int hoff = h * 64;

  if (tid < 64) rnF[tid] = 0.f;
  __syncthreads();

  #pragma unroll
  for (int chunk = 0; chunk < 2; ++chunk) {
    int u = chunk * 256 + tid;
    int t = u >> 3, p = u & 7;
    long g = rowbase + (long)t * 2048 + hoff + p * 8;
    uint4 q4 = *(const uint4*)(Cb + g);
    uint4 k4 = *(const uint4*)(Cb + g + 512);
    uint4 v4 = *(const uint4*)(Cb + g + 1024);
    uint4 a4 = *(const uint4*)(Cb + g + 1536);
    *(uint4*)&Qb[u * 8] = q4;
    *(uint4*)&Kb[u * 8] = k4;
    *(uint4*)&Vb[u * 8] = v4;
    const unsigned short* as_ = (const unsigned short*)&a4;
    unsigned short al[8];
    #pragma unroll
    for (int j = 0; j < 8; ++j) {
      float z = bf2f(as_[j]) + ba[hoff + p * 8 + j];
      al[j] = f2bf(1.f / (1.f + __expf(-z)));
    }
    uint4 pa;
    pa.x = (unsigned)al[0] | ((unsigned)al[1] << 16); pa.y = (unsigned)al[2] | ((unsigned)al[3] << 16);
    pa.z = (unsigned)al[4] | ((unsigned)al[5] << 16); pa.w = (unsigned)al[6] | ((unsigned)al[7] << 16);
    *(uint4*)&lamB[u * 8] = pa;
    const unsigned short* ks = (const unsigned short*)&k4;
    float ssq = 0.f;
    #pragma unroll
    for (int j = 0; j < 8; ++j) { float kv = bf2f(ks[j]); ssq += kv * kv; }
    atomicAdd(&rnF[t], ssq);
  }
  __syncthreads();

  if (tid < 64) {
    int d = tid; float cum = 1.f;
    #pragma unroll
    for (int t = 0; t < 64; ++t) {
      cum *= bf2f(lamB[t * 64 + d]);
      lamB[t * 64 + d] = f2bf(cum);
    }
    Dvec[(long)bhc * 64 + d] = cum;
    lendF[d] = cum;
  } else if (tid < 128) {
    int t = tid - 64;
    rnF[t] = 1.f / fmaxf(sqrtf(rnF[t]), 1e-12f);
  }
  __syncthreads();

  #pragma unroll
  for (int j = 0; j < 16; ++j) {
    int e = j * 256 + tid;
    int t = e >> 6;
    float lam = bf2f(lamB[e]);
    float kn = bf2f(Kb[e]) * rnF[t];
    Qb[e] = f2bf(bf2f(Qb[e]) * lam);
    Kb[e] = f2bf(kn / lam);
  }
  __syncthreads();

  {
    const long obase = (long)bhc * 4096;
    uint4* gq = (uint4*)(qt + obase);
    const uint4* lq = (const uint4*)Qb;
    gq[tid] = lq[tid]; gq[tid + 256] = lq[tid + 256];
  }

  const long base = (long)bhc * 4096;
  const int wave = tid >> 6, lane = tid & 63, quad = lane >> 4, l16 = lane & 15;
  const int mrow = wave * 16 + l16;
  unsigned short* Ps = lamB;

  union { short8 v; short s[8]; } aI;
  aI.v = (short8){0,0,0,0,0,0,0,0};
  {
    int target = ((wave & 1) * 16 + l16) - quad * 8;
    if (target >= 0 && target < 8) aI.s[target] = (short)0x3F80;
  }
  const int bsel = (wave >> 1) * 32;

  {
    short8 a0 = *(const short8*)&Qb[mrow * 64 + quad * 8];
    short8 a1 = *(const short8*)&Qb[mrow * 64 + 32 + quad * 8];
    #pragma unroll
    for (int nt = 0; nt < 4; ++nt) {
      short8 b0 = *(const short8*)&Kb[(nt * 16 + l16) * 64 + quad * 8];
      short8 b1 = *(const short8*)&Kb[(nt * 16 + l16) * 64 + 32 + quad * 8];
      f32x4 acc = (f32x4){0.f, 0.f, 0.f, 0.f};
      acc = __builtin_amdgcn_mfma_f32_16x16x32_bf16(a0, b0, acc, 0, 0, 0);
      acc = __builtin_amdgcn_mfma_f32_16x16x32_bf16(a1, b1, acc, 0, 0, 0);
      #pragma unroll
      for (int r = 0; r < 4; ++r) {
        int t = wave * 16 + quad * 4 + r, u = nt * 16 + l16;
        Ps[t * 64 + u] = (u <= t) ? f2bf(acc[r]) : (unsigned short)0;
      }
    }
  }
  #pragma unroll
  for (int nt = 0; nt < 4; ++nt) {
    short8 bv = *(const short8*)&Vb[(nt * 16 + l16) * 64 + bsel + quad * 8];
    short8 bk = *(const short8*)&Kb[(nt * 16 + l16) * 64 + bsel + quad * 8];
    f32x4 av = (f32x4){0.f, 0.f, 0.f, 0.f};
    f32x4 ak = (f32x4){0.f, 0.f, 0.f, 0.f};
    av = __builtin_amdgcn_mfma_f32_16x16x32_bf16(aI.v, bv, av, 0, 0, 0);
    ak = __builtin_amdgcn_mfma_f32_16x16x32_bf16(aI.v, bk, ak, 0, 0, 0);
    #pragma unroll
    for (int r = 0; r < 4; ++r) {
      int i = wave * 16 + quad * 4 + r, t = nt * 16 + l16;
      Vt[i * TS + t] = f2bf(av[r]);
      Kt[i * TS + t] = f2bf(ak[r]);
    }
  }
  __syncthreads();

  {
    short8 a0 = *(const short8*)&Ps[mrow * 64 + quad * 8];
    short8 a1 = *(const short8*)&Ps[mrow * 64 + 32 + quad * 8];
    #pragma unroll
    for (int nt = 0; nt < 4; ++nt) {
      short8 b0 = *(const short8*)&Vt[(nt * 16 + l16) * TS + quad * 8];
      short8 b1 = *(const short8*)&Vt[(nt * 16 + l16) * TS + 32 + quad * 8];
      f32x4 acc = (f32x4){0.f, 0.f, 0.f, 0.f};
      acc = __builtin_amdgcn_mfma_f32_16x16x32_bf16(a0, b0, acc, 0, 0, 0);
      acc = __builtin_amdgcn_mfma_f32_16x16x32_bf16(a1, b1, acc, 0, 0, 0);
      #pragma unroll
      for (int r = 0; r < 4; ++r) {
        int t = wave * 16 + quad * 4 + r, i = nt * 16 + l16;
        Ointra[base + t * 64 + i] = f2bf(acc[r]);
      }
    }
  }
  {
    short8 a0 = *(const short8*)&Vt[mrow * TS + quad * 8];
    short8 a1 = *(const short8*)&Vt[mrow * TS + 32 + quad * 8];
    #pragma unroll
    for (int nt = 0; nt < 4; ++nt) {
      short8 b0 = *(const short8*)&Kt[(nt * 16 + l16) * TS + quad * 8];
      short8 b1 = *(const short8*)&Kt[(nt * 16 + l16) * TS + 32 + quad * 8];
      f32x4 acc = (f32x4){0.f, 0.f, 0.f, 0.f};
      acc = __builtin_amdgcn_mfma_f32_16x16x32_bf16(a0, b0, acc, 0, 0, 0);
      acc = __builtin_amdgcn_mfma_f32_16x16x32_bf16(a1, b1, acc, 0, 0, 0);
      float le = lendF[nt * 16 + l16];
      #pragma unroll
      for (int r = 0; r < 4; ++r) {
        int i = wave * 16 + quad * 4 + r, j = nt * 16 + l16;
        Tt[base + i * 64 + j] = f2bf(acc[r] * le);
      }
    }
  }
}

// ---------------- K5: chunk-state scan, element-parallel ---------------------
__global__ __launch_bounds__(256) void scan_kernel(const unsigned short* __restrict__ Tt,
                                                   const float* __restrict__ Dvec,
                                                   unsigned short* __restrict__ Sst) {
  const int bh = blockIdx.x;
  const int e = blockIdx.y * 256 + threadIdx.x;
  const int j = e & 63;
  float S = 0.f;
  for (int c = 0; c < 64; ++c) {
    const long idx = ((long)(bh * 64 + c)) * 4096 + e;
    const float dj = Dvec[((long)(bh * 64 + c)) * 64 + j];
    Sst[idx] = f2bf(S);
    S = dj * S + bf2f(Tt[idx]);
  }
}

// ---------------- K6: O = O_intra + q~ @ S_prev --------------------------
__global__ __launch_bounds__(256) void combine_kernel(const unsigned short* __restrict__ qt,
                                                      const unsigned short* __restrict__ Sst,
                                                      const unsigned short* __restrict__ Ointra,
                                                      unsigned short* __restrict__ O) {
  const int bhc = blockIdx.x;
  const int c = bhc & 63, bh = bhc >> 6;
  const int h = bh & 7, b = bh >> 3;
  const long base = (long)bhc * 4096;
  __shared__ __align__(16) unsigned short Qs[4096], Sb[4096];
  const int tid = threadIdx.x;
  {
    const uint4* gq = (const uint4*)(qt + base);  uint4* lq = (uint4*)Qs;
    const uint4* gs = (const uint4*)(Sst + base); uint4* ls = (uint4*)Sb;
    lq[tid] = gq[tid]; lq[tid + 256] = gq[tid + 256];
    ls[tid] = gs[tid]; ls[tid + 256] = gs[tid + 256];
  }
  __syncthreads();
  const int wave = tid >> 6, lane = tid & 63, quad = lane >> 4, l16 = lane & 15;
  const int mrow = wave * 16 + l16;
  short8 a0 = *(const short8*)&Qs[mrow * 64 + quad * 8];
  short8 a1 = *(const short8*)&Qs[mrow * 64 + 32 + quad * 8];
  #pragma unroll
  for (int nt = 0; nt < 4; ++nt) {
    f32x4 acc;
    #pragma unroll
    for (int r = 0; r < 4; ++r) {
      int t = wave * 16 + quad * 4 + r, i = nt * 16 + l16;
      acc[r] = bf2f(Ointra[base + t * 64 + i]);
    }
    short8 b0 = *(const short8*)&Sb[(nt * 16 + l16) * 64 + quad * 8];
    short8 b1 = *(const short8*)&Sb[(nt * 16 + l16) * 64 + 32 + quad * 8];
    acc = __builtin_amdgcn_mfma_f32_16x16x32_bf16(a0, b0, acc, 0, 0, 0);
    acc = __builtin_amdgcn_mfma_f32_16x16x32_bf16(a1, b1, acc, 0, 0, 0);
    #pragma unroll
    for (int r = 0; r < 4; ++r) {
      int t = wave * 16 + quad * 4 + r, i = nt * 16 + l16;
      O[((long)(b * 4096 + c * 64 + t)) * 512 + h * 64 + i] = f2bf(acc[r]);
    }
  }
}

// ---------------- host ----------------
extern "C" void kernel_launch(void* const* d_in, const int* in_sizes, int n_in,
                              void* d_out, int out_size, void* d_ws, size_t ws_size,
                              hipStream_t stream) {
  const float* x     = (const float*)d_in[0];
  const float* Wq    = (const float*)d_in[1];
  const float* Wk    = (const float*)d_in[2];
  const float* Wv    = (const float*)d_in[3];
  const float* Wa    = (const float*)d_in[4];
  const float* ba    = (const float*)d_in[5];
  const float* Wo    = (const float*)d_in[6];
  const float* gamma = (const float*)d_in[7];
  const float* beta  = (const float*)d_in[8];
  float* out = (float*)d_out;

  char* ws = (char*)d_ws;
  const size_t KB = 1024;
  unsigned short* Wt     = (unsigned short*)(ws + 0 * KB);
  unsigned short* Wot    = (unsigned short*)(ws + 4096 * KB);
  float*          Dvec   = (float*)         (ws + 5120 * KB);
  unsigned short* qt     = (unsigned short*)(ws + 5632 * KB);
  unsigned short* Ttb    = (unsigned short*)(ws + 22016 * KB);
  unsigned short* Sst    = (unsigned short*)(ws + 38400 * KB);
  unsigned short* xn     = (unsigned short*)(ws + 54784 * KB);
  unsigned short* Ointra = (unsigned short*)(ws + 54784 * KB);
  unsigned short* Ob     = (unsigned short*)(ws + 71168 * KB);
  unsigned short* Cb     = (unsigned short*)(ws + 87552 * KB);

  init_kernel<<<NTOK + 2048 + 512, 256, 0, stream>>>(x, gamma, beta, Wq, Wk, Wv, Wa, Wo, xn, Wt, Wot);
  gemm8<0><<<512, 512, 0, stream>>>(xn, Wt, Cb, nullptr, nullptr, NTOK, 2048, 1024);
  prep_intra_kernel<<<NBHC, 256, 0, stream>>>(Cb, ba, qt, Dvec, Ointra, Ttb);
  scan_kernel<<<dim3(32, 16), 256, 0, stream>>>(Ttb, Dvec, Sst);
  combine_kernel<<<NBHC, 256, 0, stream>>>(qt, Sst, Ointra, Ob);
  gemm8<1><<<256, 512, 0, stream>>>(Ob, Wot, nullptr, out, x, NTOK, 1024, 512);
}